// Round 3
// baseline (755.155 us; speedup 1.0000x reference)
//
#include <hip/hip_runtime.h>
#include <hip/hip_bf16.h>
#include <stdint.h>

// Problem constants (fixed by setup_inputs)
#define HEADS 8
#define HD 32          // head dim
#define WS2 64         // 8*8 tokens per kv window
#define NQ 256         // M*WS2 queries per window
#define NWIN 1024      // B * nW = 4 * 256

typedef unsigned short u16;
typedef __bf16 bf16x8_t __attribute__((ext_vector_type(8)));
typedef float f32x4_t __attribute__((ext_vector_type(4)));
typedef unsigned short u16x8 __attribute__((ext_vector_type(8)));

// fp32 -> bf16 round-to-nearest-even
__device__ __forceinline__ u16 f2b(float x) {
  uint32_t u = __builtin_bit_cast(uint32_t, x);
  u += 0x7FFFu + ((u >> 16) & 1u);
  return (u16)(u >> 16);
}

__device__ __forceinline__ f32x4_t mfma_bf16(u16x8 a, u16x8 b, f32x4_t c) {
  return __builtin_amdgcn_mfma_f32_16x16x32_bf16(
      __builtin_bit_cast(bf16x8_t, a), __builtin_bit_cast(bf16x8_t, b), c, 0, 0, 0);
}

// ---------------------------------------------------------------------------
// Prep: bf16-transpose weights ([K][N] -> [N][K]) + build bias0[h][64][64]
// grid 512 x 256 = 131072 threads
// ---------------------------------------------------------------------------
__global__ void prep_kernel(const float* __restrict__ Wq, const float* __restrict__ Wkv,
                            const float* __restrict__ Wp, const float* __restrict__ btab,
                            u16* __restrict__ WqT, u16* __restrict__ WkvT,
                            u16* __restrict__ WpT, float* __restrict__ bias0) {
  int tid = blockIdx.x * 256 + threadIdx.x;  // 0..131071
  {
    int n = tid >> 8, k = tid & 255;          // WkvT[n][k] = Wkv[k][n], n<512
    WkvT[tid] = f2b(Wkv[k * 512 + n]);
  }
  if (tid < 65536) {
    int n = tid >> 8, k = tid & 255;
    WqT[tid] = f2b(Wq[k * 256 + n]);
    WpT[tid] = f2b(Wp[k * 256 + n]);
  }
  if (tid < 32768) {  // bias0[h][q][k], q,k in [0,64)
    int h = tid >> 12, q = (tid >> 6) & 63, k = tid & 63;
    int qy = q >> 3, qx = q & 7, ky = k >> 3, kx = k & 7;
    int idx = (qy - ky + 7) * 15 + (qx - kx + 7);
    bias0[tid] = btab[idx * HEADS + h];
  }
}

// ---------------------------------------------------------------------------
// Tiled bf16 MFMA GEMM: C[M][N] = A[M][256] * W[256][N] + bias
// block = 512 thr (8 waves, 2x4), tile BM=128 BN=256 BK=64
// A modes: 0 = gauss rows (fp32), 1 = window-gathered image rows (fp32),
//          2 = attention-O gather from qo buffer (bf16)
// E modes: 0 = Q layout [win][h][q][d] bf16, 1 = K/V split, 2 = fp32 identity
// LDS strides +8 u16 (16B): ds_read_b128 lands ~2-way bank aliasing (free).
// ---------------------------------------------------------------------------
#define A_GAUSS 0
#define A_IMG 1
#define A_OBUF 2
#define E_Q 0
#define E_KV 1
#define E_OUT 2

template <int AMODE, int EMODE>
__global__ __launch_bounds__(512) void gemm_proj(
    const float* __restrict__ Af, const u16* __restrict__ Ab,
    const u16* __restrict__ WT, const float* __restrict__ bias,
    u16* __restrict__ qo, u16* __restrict__ kb, u16* __restrict__ vt,
    float* __restrict__ outp) {
  __shared__ u16 Asm[128 * 72];  // [128][64+8]
  __shared__ u16 Bsm[256 * 72];  // B^T tile: [n][k]
  const int tid = threadIdx.x;
  const int bx = blockIdx.x;
  const int n0 = blockIdx.y * 256;
  const int lane = tid & 63, wid = tid >> 6;
  const int wm = wid & 1, wn = wid >> 1;     // 2 x 4 wave grid
  const int lr = lane & 15, lg = lane >> 4;

  f32x4_t acc[4][4] = {};

  const int srow = tid >> 2;        // A staging: 0..127
  const int scb = (tid & 3) * 16;   // 0,16,32,48
  const int bn = tid >> 1;          // B staging: 0..255
  const int bkb = (tid & 1) * 32;   // 0,32

  for (int kt0 = 0; kt0 < 256; kt0 += 64) {
    // ---- stage A tile [128][64] bf16
    if constexpr (AMODE == A_OBUF) {
      int t = bx * 128 + srow;
      int win = t >> 8, qq = t & 255;
      int c0 = kt0 + scb, head = c0 >> 5, off = c0 & 31;  // off in {0,16}
      const u16* src = Ab + (size_t)(win * 8 + head) * 8192 + qq * 32 + off;
      *(u16x8*)&Asm[srow * 72 + scb] = *(const u16x8*)src;
      *(u16x8*)&Asm[srow * 72 + scb + 8] = *(const u16x8*)(src + 8);
    } else {
      const float* src;
      if constexpr (AMODE == A_GAUSS) {
        src = Af + (size_t)(bx * 128 + srow) * 256 + kt0 + scb;
      } else {  // A_IMG: window partition gather
        int t = bx * 128 + srow;
        int win = t >> 6, key = t & 63;
        int b_ = win >> 8, wy = (win >> 4) & 15, wx = win & 15;
        int y = key >> 3, x = key & 7;
        src = Af + ((size_t)(b_ * 128 + wy * 8 + y) * 128 + (wx * 8 + x)) * 256 + kt0 + scb;
      }
      float4 v0 = ((const float4*)src)[0];
      float4 v1 = ((const float4*)src)[1];
      float4 v2 = ((const float4*)src)[2];
      float4 v3 = ((const float4*)src)[3];
      u16x8 o0 = {f2b(v0.x), f2b(v0.y), f2b(v0.z), f2b(v0.w),
                  f2b(v1.x), f2b(v1.y), f2b(v1.z), f2b(v1.w)};
      u16x8 o1 = {f2b(v2.x), f2b(v2.y), f2b(v2.z), f2b(v2.w),
                  f2b(v3.x), f2b(v3.y), f2b(v3.z), f2b(v3.w)};
      *(u16x8*)&Asm[srow * 72 + scb] = o0;
      *(u16x8*)&Asm[srow * 72 + scb + 8] = o1;
    }
    // ---- stage B tile: Bsm[n][k] = W[k][n0+n] = WT[n0+n][k], contiguous copy
    {
      const u16* src = WT + (size_t)(n0 + bn) * 256 + kt0 + bkb;
      u16x8 b0 = ((const u16x8*)src)[0];
      u16x8 b1 = ((const u16x8*)src)[1];
      u16x8 b2 = ((const u16x8*)src)[2];
      u16x8 b3 = ((const u16x8*)src)[3];
      *(u16x8*)&Bsm[bn * 72 + bkb + 0] = b0;
      *(u16x8*)&Bsm[bn * 72 + bkb + 8] = b1;
      *(u16x8*)&Bsm[bn * 72 + bkb + 16] = b2;
      *(u16x8*)&Bsm[bn * 72 + bkb + 24] = b3;
    }
    __syncthreads();
    // ---- MFMA: 2 k-steps of 32
#pragma unroll
    for (int ks = 0; ks < 2; ++ks) {
      u16x8 af[4], bfr[4];
#pragma unroll
      for (int mt = 0; mt < 4; ++mt)
        af[mt] = *(const u16x8*)&Asm[(wm * 64 + mt * 16 + lr) * 72 + ks * 32 + lg * 8];
#pragma unroll
      for (int nt = 0; nt < 4; ++nt)
        bfr[nt] = *(const u16x8*)&Bsm[(wn * 64 + nt * 16 + lr) * 72 + ks * 32 + lg * 8];
#pragma unroll
      for (int mt = 0; mt < 4; ++mt)
#pragma unroll
        for (int nt = 0; nt < 4; ++nt)
          acc[mt][nt] = mfma_bf16(af[mt], bfr[nt], acc[mt][nt]);
    }
    __syncthreads();
  }

  // ---- epilogue: D layout col = lane&15, row = 4*(lane>>4)+reg
#pragma unroll
  for (int nt = 0; nt < 4; ++nt) {
    const int col = n0 + wn * 64 + nt * 16 + lr;
    const float bv = bias[col];
#pragma unroll
    for (int mt = 0; mt < 4; ++mt) {
#pragma unroll
      for (int r = 0; r < 4; ++r) {
        int row = bx * 128 + wm * 64 + mt * 16 + lg * 4 + r;
        float v = acc[mt][nt][r] + bv;
        if constexpr (EMODE == E_Q) {
          int win = row >> 8, q = row & 255, h = col >> 5, d = col & 31;
          qo[(size_t)(win * 8 + h) * 8192 + q * 32 + d] = f2b(v);
        } else if constexpr (EMODE == E_KV) {
          int win = row >> 6, key = row & 63;
          if (col < 256) {  // K: [win][h][key][d]
            int h = col >> 5, d = col & 31;
            kb[(size_t)(win * 8 + h) * 2048 + key * 32 + d] = f2b(v);
          } else {          // V transposed: [win][h][d][key]
            int c = col - 256, h = c >> 5, d = c & 31;
            vt[(size_t)(win * 8 + h) * 2048 + d * 64 + key] = f2b(v);
          }
        } else {  // E_OUT: final fp32, identity layout
          outp[(size_t)row * 256 + col] = v;
        }
      }
    }
  }
}

// ---------------------------------------------------------------------------
// Fused attention per (window, head): 256 thr = 4 waves, each wave owns 64 q.
// S = Q K^T * scale + bias ; in-register softmax ; O = P V, written IN PLACE
// over the Q slice (each wave only writes rows it alone read -> race-free).
// ---------------------------------------------------------------------------
__global__ __launch_bounds__(256) void attn_kernel(
    u16* qo,  // [win][h][256 q][32 d] bf16, Q in / O out (aliased)
    const u16* __restrict__ kb,    // [win][h][64 key][32 d]
    const u16* __restrict__ vt,    // [win][h][32 d][64 key]
    const float* __restrict__ bias0) {  // [h][64][64]
  __shared__ u16 P[4][64 * 72];  // per-wave P tile, +8 pad
  const int blk = blockIdx.x;
  const int win = blk >> 3, h = blk & 7;
  const int tid = threadIdx.x, lane = tid & 63, w = tid >> 6;
  const int lr = lane & 15, lg = lane >> 4;
  const size_t qbase = (size_t)(win * 8 + h) * 8192;
  const size_t kvbase = (size_t)(win * 8 + h) * 2048;
  const float* bb = bias0 + h * 4096;
  const float scale = 0.17677669529663687f;  // 32^-0.5

  // Q fragments (A: row=q, k=d) and K fragments (B: col=key, k=d): direct
  // global loads, both contiguous 16B per lane.
  u16x8 qf[4], kf[4];
#pragma unroll
  for (int kt = 0; kt < 4; ++kt)
    kf[kt] = *(const u16x8*)(kb + kvbase + (kt * 16 + lr) * 32 + lg * 8);
#pragma unroll
  for (int qt = 0; qt < 4; ++qt)
    qf[qt] = *(const u16x8*)(qo + qbase + (w * 64 + qt * 16 + lr) * 32 + lg * 8);

  f32x4_t s[4][4];
#pragma unroll
  for (int qt = 0; qt < 4; ++qt)
#pragma unroll
    for (int kt = 0; kt < 4; ++kt) {
      f32x4_t z = {};
      s[qt][kt] = mfma_bf16(qf[qt], kf[kt], z);
    }

  // scale + bias + softmax over 64 keys. Row q lives on 16 lanes (same lg)
  // x 4 kt regs; reduce via 4 shfl_xor (bits 0..3 = lr).
#pragma unroll
  for (int qt = 0; qt < 4; ++qt) {
#pragma unroll
    for (int r = 0; r < 4; ++r) {
      int ql = qt * 16 + lg * 4 + r;  // q mod 64 == bias row
      float v0 = s[qt][0][r] * scale + bb[ql * 64 + 0 + lr];
      float v1 = s[qt][1][r] * scale + bb[ql * 64 + 16 + lr];
      float v2 = s[qt][2][r] * scale + bb[ql * 64 + 32 + lr];
      float v3 = s[qt][3][r] * scale + bb[ql * 64 + 48 + lr];
      float m = fmaxf(fmaxf(v0, v1), fmaxf(v2, v3));
      m = fmaxf(m, __shfl_xor(m, 1));
      m = fmaxf(m, __shfl_xor(m, 2));
      m = fmaxf(m, __shfl_xor(m, 4));
      m = fmaxf(m, __shfl_xor(m, 8));
      v0 = __expf(v0 - m); v1 = __expf(v1 - m);
      v2 = __expf(v2 - m); v3 = __expf(v3 - m);
      float sum = v0 + v1 + v2 + v3;
      sum += __shfl_xor(sum, 1);
      sum += __shfl_xor(sum, 2);
      sum += __shfl_xor(sum, 4);
      sum += __shfl_xor(sum, 8);
      float inv = 1.f / sum;
      P[w][ql * 72 + 0 + lr] = f2b(v0 * inv);
      P[w][ql * 72 + 16 + lr] = f2b(v1 * inv);
      P[w][ql * 72 + 32 + lr] = f2b(v2 * inv);
      P[w][ql * 72 + 48 + lr] = f2b(v3 * inv);
    }
  }
  __syncthreads();

  // V fragments (B: col=d, k=key) from transposed V: contiguous 16B.
  u16x8 vf[2][2];
#pragma unroll
  for (int dt = 0; dt < 2; ++dt)
#pragma unroll
    for (int ks = 0; ks < 2; ++ks)
      vf[dt][ks] = *(const u16x8*)(vt + kvbase + (dt * 16 + lr) * 64 + ks * 32 + lg * 8);

#pragma unroll
  for (int qt = 0; qt < 4; ++qt) {
    f32x4_t o[2];
    o[0] = {}; o[1] = {};
#pragma unroll
    for (int ks = 0; ks < 2; ++ks) {
      u16x8 pf = *(const u16x8*)&P[w][(qt * 16 + lr) * 72 + ks * 32 + lg * 8];
#pragma unroll
      for (int dt = 0; dt < 2; ++dt)
        o[dt] = mfma_bf16(pf, vf[dt][ks], o[dt]);
    }
#pragma unroll
    for (int dt = 0; dt < 2; ++dt)
#pragma unroll
      for (int r = 0; r < 4; ++r) {
        int q = w * 64 + qt * 16 + lg * 4 + r;
        int d = dt * 16 + lr;
        qo[qbase + q * 32 + d] = f2b(o[dt][r]);  // O over Q, per-wave rows
      }
  }
}

// ---------------------------------------------------------------------------
// Workspace layout (bytes):
//   qo    @ 0          : 134,217,728  (Q then O, bf16 [win][h][256][32])
//   kb    @ 134217728  :  33,554,432
//   vt    @ 167772160  :  33,554,432
//   WqT   @ 201326592  :     131,072
//   WkvT  @ 201457664  :     262,144
//   WpT   @ 201719808  :     131,072
//   bias0 @ 201850880  :     131,072
// total ~193 MB
// ---------------------------------------------------------------------------
extern "C" void kernel_launch(void* const* d_in, const int* in_sizes, int n_in,
                              void* d_out, int out_size, void* d_ws, size_t ws_size,
                              hipStream_t stream) {
  const float* gauss = (const float*)d_in[0];
  const float* image = (const float*)d_in[1];
  const float* btab  = (const float*)d_in[2];
  const float* Wq    = (const float*)d_in[3];
  const float* bq    = (const float*)d_in[4];
  const float* Wkv   = (const float*)d_in[5];
  const float* bkv   = (const float*)d_in[6];
  const float* Wp    = (const float*)d_in[7];
  const float* bp    = (const float*)d_in[8];
  float* out = (float*)d_out;

  char* ws = (char*)d_ws;
  u16* qo    = (u16*)(ws);
  u16* kb    = (u16*)(ws + 134217728);
  u16* vtb   = (u16*)(ws + 167772160);
  u16* wqT   = (u16*)(ws + 201326592);
  u16* wkvT  = (u16*)(ws + 201457664);
  u16* wpT   = (u16*)(ws + 201719808);
  float* b0  = (float*)(ws + 201850880);

  prep_kernel<<<512, 256, 0, stream>>>(Wq, Wkv, Wp, btab, wqT, wkvT, wpT, b0);

  // Q = gauss @ Wq + bq  -> qo
  gemm_proj<A_GAUSS, E_Q><<<dim3(2048, 1), 512, 0, stream>>>(
      gauss, nullptr, wqT, bq, qo, nullptr, nullptr, nullptr);
  // KV = win(image) @ Wkv + bkv -> kb, vt
  gemm_proj<A_IMG, E_KV><<<dim3(512, 2), 512, 0, stream>>>(
      image, nullptr, wkvT, bkv, nullptr, kb, vtb, nullptr);
  // attention: O overwrites Q slice
  attn_kernel<<<8192, 256, 0, stream>>>(qo, kb, vtb, b0);
  // out = O @ Wp + bp -> d_out (fp32)
  gemm_proj<A_OBUF, E_OUT><<<dim3(2048, 1), 512, 0, stream>>>(
      nullptr, qo, wpT, bp, nullptr, nullptr, nullptr, out);
}